// Round 2
// baseline (488.188 us; speedup 1.0000x reference)
//
#include <hip/hip_runtime.h>

#define FEAT   512
#define MEMN   256
#define BATCH  512
#define PROMPT 131072   // 64*2048 flattened
#define TOPK   16
#define EPSF   1e-8f

// ctx tiling
#define CCOLS  32                 // columns per chunk (LDS slab width)
#define NCH    32                 // chunks per block
#define NGRP   128                // column groups: 131072 / (CCOLS*NCH)
#define BT     128                // batches per block
#define NTILE  4                  // 512 / BT
#define CTPB   512                // ctx threads per block (8 waves)

// ---------------------------------------------------------------------------
// Kernel A0: normalize keys -> kn (workspace). One block per key row.
// ---------------------------------------------------------------------------
__global__ __launch_bounds__(256) void knorm_kernel(
    const float* __restrict__ keys, float* __restrict__ kn)
{
    __shared__ float red[4];
    const int m = blockIdx.x;
    const int tid = threadIdx.x;
    float2 v = *reinterpret_cast<const float2*>(keys + m * FEAT + tid * 2);
    float p = v.x * v.x + v.y * v.y;
    for (int off = 32; off; off >>= 1) p += __shfl_down(p, off);
    if ((tid & 63) == 0) red[tid >> 6] = p;
    __syncthreads();
    float s = red[0] + red[1] + red[2] + red[3];
    float nrm = sqrtf(s); if (nrm < EPSF) nrm = EPSF;
    const float inv = 1.0f / nrm;
    float2 o; o.x = v.x * inv; o.y = v.y * inv;
    *reinterpret_cast<float2*>(kn + m * FEAT + tid * 2) = o;
}

// ---------------------------------------------------------------------------
// Kernel A: sim = (f/|f|) . kn^T, top-16, clamp+renorm weights.
// ---------------------------------------------------------------------------
__global__ __launch_bounds__(256) void topk_kernel(
    const float* __restrict__ features,
    const float* __restrict__ kn,
    int* __restrict__ out_ids,
    float* __restrict__ out_w)
{
    __shared__ float f_lds[FEAT];
    __shared__ float sim_lds[MEMN];
    __shared__ float red[4];

    const int b = blockIdx.x;
    const int tid = threadIdx.x;

    // stage f + compute |f|^2
    float2 fv = *reinterpret_cast<const float2*>(features + b * FEAT + tid * 2);
    *reinterpret_cast<float2*>(f_lds + tid * 2) = fv;
    float p = fv.x * fv.x + fv.y * fv.y;
    for (int off = 32; off; off >>= 1) p += __shfl_down(p, off);
    if ((tid & 63) == 0) red[tid >> 6] = p;
    __syncthreads();
    const float f2 = red[0] + red[1] + red[2] + red[3];
    float fn = sqrtf(f2); if (fn < EPSF) fn = EPSF;
    const float invf = 1.0f / fn;

    // sim: wave handles 4 rows x 16 lanes each, 16 passes
    const int wave = tid >> 6, lane = tid & 63;
    const int jc = lane & 15, msub = lane >> 4;
    for (int pss = 0; pss < 16; ++pss) {
        const int m = pss * 16 + wave * 4 + msub;
        const float* krow = kn + m * FEAT;
        float dot = 0.f;
#pragma unroll
        for (int s = 0; s < 8; ++s) {
            float4 kv = *reinterpret_cast<const float4*>(krow + s * 64 + jc * 4);
            float4 fw = *reinterpret_cast<const float4*>(f_lds + s * 64 + jc * 4);
            dot += kv.x * fw.x + kv.y * fw.y + kv.z * fw.z + kv.w * fw.w;
        }
        dot += __shfl_xor(dot, 1); dot += __shfl_xor(dot, 2);
        dot += __shfl_xor(dot, 4); dot += __shfl_xor(dot, 8);
        if (jc == 0) sim_lds[m] = dot * invf;
    }
    __syncthreads();

    // single-wave top-16 (tie -> lowest index, matches jax.lax.top_k)
    if (tid < 64) {
        const int lane_ = tid;
        float v0 = sim_lds[lane_];
        float v1 = sim_lds[lane_ + 64];
        float v2 = sim_lds[lane_ + 128];
        float v3 = sim_lds[lane_ + 192];
        int myid = 0;

        for (int r = 0; r < TOPK; ++r) {
            float bv = v0; int bi = lane_;
            if (v1 > bv) { bv = v1; bi = lane_ + 64;  }
            if (v2 > bv) { bv = v2; bi = lane_ + 128; }
            if (v3 > bv) { bv = v3; bi = lane_ + 192; }
            for (int off = 32; off > 0; off >>= 1) {
                const float ov = __shfl_down(bv, off);
                const int   oi = __shfl_down(bi, off);
                if (ov > bv || (ov == bv && oi < bi)) { bv = ov; bi = oi; }
            }
            bi = __shfl(bi, 0);
            if (lane_ == r) myid = bi;
            if ((bi & 63) == lane_) {
                const int slot = bi >> 6;
                if      (slot == 0) v0 = -1e30f;
                else if (slot == 1) v1 = -1e30f;
                else if (slot == 2) v2 = -1e30f;
                else                v3 = -1e30f;
            }
        }

        if (lane_ < TOPK) {
            float val = sim_lds[myid];
            if (val < 0.f) val = 0.f;
            float s = val;
            for (int off = 1; off < TOPK; off <<= 1)
                s += __shfl_xor(s, off);
            out_ids[b * TOPK + lane_] = myid;
            out_w[b * TOPK + lane_]   = val / s;
        }
    }
}

// ---------------------------------------------------------------------------
// Kernel B: ctx[b, col] = sum_k w[b,k] * mem[id[b,k], col]
// 512 blocks x 512 threads (8 waves): 2 blocks/CU, 16 waves/CU (4/SIMD).
// Each block owns 128 batches x 1024 cols; each lane owns 2 batches
// (off[32]/w[32] = 64 VGPRs -> fits the 128-VGPR cap of 4 waves/SIMD).
// Double-buffered 2x32 KB slabs; stage chunk c+1 overlaps compute of chunk c;
// counted s_waitcnt vmcnt(2) (2 trailing stores) + raw s_barrier, 1 barrier
// per chunk. XCD swizzle keeps a group's 4 batch-tiles co-resident per XCD.
// ---------------------------------------------------------------------------
__global__ __launch_bounds__(CTPB, 4) void ctx_kernel(
    const float* __restrict__ mem,
    const int* __restrict__ ids,
    const float* __restrict__ wgt,
    float* __restrict__ out)
{
    __shared__ float slab0[MEMN * CCOLS];   // 32 KB
    __shared__ float slab1[MEMN * CCOLS];   // 32 KB

    const int bid  = blockIdx.x;
    const int xcd  = bid & 7;
    const int idx  = bid >> 3;
    const int tile = idx >> 4;                 // 0..3
    const int g    = xcd * 16 + (idx & 15);    // 0..127, tiles of a group co-XCD
    const int b_base = tile * BT;
    const int col0   = g * (NCH * CCOLS);      // 1024-col swath

    const int tid  = threadIdx.x;
    const int wave = tid >> 6, lane = tid & 63;
    const int bg   = lane >> 3;                // batch sub-group 0..7
    const int cg   = lane & 7;                 // col group 0..7 (4 floats each)

    const int bA = b_base + wave * 8 + bg;     // batches bA, bA+64

    // (id, w) -> registers for the whole kernel; ids pre-scaled to LDS byte offs
    int   off[2 * TOPK];
    float w[2 * TOPK];
#pragma unroll
    for (int q = 0; q < 2; ++q) {
        const int b = bA + q * 64;
#pragma unroll
        for (int r = 0; r < 4; ++r) {
            int4   iv = *reinterpret_cast<const int4*>(ids + b * TOPK + r * 4);
            float4 wv = *reinterpret_cast<const float4*>(wgt + b * TOPK + r * 4);
            off[q*16 + r*4 + 0] = iv.x * (CCOLS*4) + cg * 16;
            off[q*16 + r*4 + 1] = iv.y * (CCOLS*4) + cg * 16;
            off[q*16 + r*4 + 2] = iv.z * (CCOLS*4) + cg * 16;
            off[q*16 + r*4 + 3] = iv.w * (CCOLS*4) + cg * 16;
            w[q*16 + r*4 + 0] = wv.x; w[q*16 + r*4 + 1] = wv.y;
            w[q*16 + r*4 + 2] = wv.z; w[q*16 + r*4 + 3] = wv.w;
        }
    }

    // stage 256 rows x 128 B into buf; each wave: 4 iters x (8 rows x 128 B)
    auto stage = [&](float* buf, int cb) {
#pragma unroll
        for (int i = 0; i < 4; ++i) {
            const int r = wave * 32 + i * 8 + bg;
            const float* gp = mem + (size_t)r * PROMPT + cb + cg * 4;
            float* lp = buf + (wave * 32 + i * 8) * CCOLS + lane * 4;
            __builtin_amdgcn_global_load_lds(
                (const __attribute__((address_space(1))) unsigned int*)gp,
                (__attribute__((address_space(3))) unsigned int*)lp,
                16, 0, 0);
        }
    };

    // gather-accumulate 2 batches x 8 float4-cols from buf, 2 stores
    auto compute = [&](const float* buf, int cb) {
        const char* slb = reinterpret_cast<const char*>(buf);
#pragma unroll
        for (int q = 0; q < 2; ++q) {
            float4 acc;
            acc.x = acc.y = acc.z = acc.w = 0.f;
#pragma unroll
            for (int k = 0; k < TOPK; ++k) {
                const float4 v = *reinterpret_cast<const float4*>(slb + off[q*16 + k]);
                const float ww = w[q*16 + k];
                acc.x += ww * v.x; acc.y += ww * v.y;
                acc.z += ww * v.z; acc.w += ww * v.w;
            }
            const int b = bA + q * 64;
            *reinterpret_cast<float4*>(out + (size_t)b * PROMPT + cb + cg * 4) = acc;
        }
    };

    // prologue: fill slab0 with chunk 0
    stage(slab0, col0);
    asm volatile("s_waitcnt vmcnt(0)" ::: "memory");
    __builtin_amdgcn_s_barrier();
    asm volatile("" ::: "memory");

    for (int c = 0; c < NCH; c += 2) {
        // stage c+1 -> slab1 while computing c from slab0
        stage(slab1, col0 + (c + 1) * CCOLS);
        asm volatile("" ::: "memory");
        compute(slab0, col0 + c * CCOLS);
        asm volatile("s_waitcnt vmcnt(2)" ::: "memory");   // 2 stores may remain
        __builtin_amdgcn_s_barrier();
        asm volatile("" ::: "memory");

        // stage c+2 -> slab0 while computing c+1 from slab1
        if (c + 2 < NCH) stage(slab0, col0 + (c + 2) * CCOLS);
        asm volatile("" ::: "memory");
        compute(slab1, col0 + (c + 1) * CCOLS);
        asm volatile("s_waitcnt vmcnt(2)" ::: "memory");
        __builtin_amdgcn_s_barrier();
        asm volatile("" ::: "memory");
    }
}

extern "C" void kernel_launch(void* const* d_in, const int* in_sizes, int n_in,
                              void* d_out, int out_size, void* d_ws, size_t ws_size,
                              hipStream_t stream) {
    const float* features = (const float*)d_in[0];   // (512, 512)
    const float* keys     = (const float*)d_in[1];   // (256, 512)
    const float* mem      = (const float*)d_in[2];   // (256, 131072)
    float* out = (float*)d_out;                      // (512, 131072)

    char* ws = (char*)d_ws;
    int*   ids = (int*)ws;                               // 32 KB
    float* wgt = (float*)(ws + 32768);                   // 32 KB
    float* kn  = (float*)(ws + 65536);                   // 512 KB

    knorm_kernel<<<MEMN, 256, 0, stream>>>(keys, kn);
    topk_kernel<<<BATCH, 256, 0, stream>>>(features, kn, ids, wgt);
    ctx_kernel<<<NTILE * NGRP, CTPB, 0, stream>>>(mem, ids, wgt, out);
}

// Round 4
// 451.796 us; speedup vs baseline: 1.0806x; 1.0806x over previous
//
#include <hip/hip_runtime.h>

#define FEAT   512
#define MEMN   256
#define BATCH  512
#define PROMPT 131072   // 64*2048 flattened
#define TOPK   16
#define EPSF   1e-8f

// sim tiling
#define SB 8    // batches per sim block
#define SK 32   // keys per sim block

// ctx tiling (round-1 winning config)
#define CCOLS  32                 // columns per chunk (LDS slab width)
#define NCH    32                 // chunks per block
#define NGRP   128                // column groups: 131072 / (CCOLS*NCH)
#define BT     128                // batches per block
#define NTILE  4                  // 512 / BT

// ---------------------------------------------------------------------------
// Kernel 1: sim[b][m] = (f_b . k_m) / max(|k_m|, eps).
// |f_b| is NOT divided out: it is a positive per-batch constant, so top-k
// order, the 0-clamp, and the renormalized weights are unchanged.
// Block: 8 batches x 32 keys; f rows staged in LDS (16 KB); each key row is
// read ONCE per block with 8-way reuse; key self-dot fused (no knorm pass).
// 2 passes of 32-deep independent FMA chains -> latency-proof.
// ---------------------------------------------------------------------------
__global__ __launch_bounds__(256) void sim_kernel(
    const float* __restrict__ features,
    const float* __restrict__ keys,
    float* __restrict__ sim)
{
    __shared__ float f_lds[SB * FEAT];   // 16 KB

    const int bg = blockIdx.x >> 3;      // 0..63
    const int kg = blockIdx.x & 7;       // 0..7
    const int b0 = bg * SB;
    const int k0 = kg * SK;
    const int tid = threadIdx.x;

    // stage 8 feature rows, coalesced (each half-wave reads 512 B runs)
    {
        const int r = tid >> 5, c = tid & 31;
#pragma unroll
        for (int q = 0; q < 4; ++q) {
            float4 v = *reinterpret_cast<const float4*>(
                features + (size_t)(b0 + r) * FEAT + (c + q * 32) * 4);
            *reinterpret_cast<float4*>(f_lds + r * FEAT + (c + q * 32) * 4) = v;
        }
    }
    __syncthreads();

    const int wave = tid >> 6, lane = tid & 63;
    const int jc = lane & 15, msub = lane >> 4;

#pragma unroll
    for (int p = 0; p < 2; ++p) {
        const int mloc = p * 16 + wave * 4 + msub;       // 0..31
        const float* krow = keys + (size_t)(k0 + mloc) * FEAT;
        float dot[SB];
        float kk = 0.f;
#pragma unroll
        for (int b = 0; b < SB; ++b) dot[b] = 0.f;
#pragma unroll
        for (int s = 0; s < 8; ++s) {
            float4 kv = *reinterpret_cast<const float4*>(krow + s * 64 + jc * 4);
            kk += kv.x * kv.x + kv.y * kv.y + kv.z * kv.z + kv.w * kv.w;
#pragma unroll
            for (int b = 0; b < SB; ++b) {
                float4 fw = *reinterpret_cast<const float4*>(
                    f_lds + b * FEAT + s * 64 + jc * 4);
                dot[b] += kv.x * fw.x + kv.y * fw.y + kv.z * fw.z + kv.w * fw.w;
            }
        }
        // reduce across the 16 jc lanes (xor masks < 16 stay in-group)
#pragma unroll
        for (int b = 0; b < SB; ++b) {
            dot[b] += __shfl_xor(dot[b], 1); dot[b] += __shfl_xor(dot[b], 2);
            dot[b] += __shfl_xor(dot[b], 4); dot[b] += __shfl_xor(dot[b], 8);
        }
        kk += __shfl_xor(kk, 1); kk += __shfl_xor(kk, 2);
        kk += __shfl_xor(kk, 4); kk += __shfl_xor(kk, 8);

        if (jc == 0) {
            float nrm = sqrtf(kk); if (nrm < EPSF) nrm = EPSF;
            const float inv = 1.0f / nrm;
#pragma unroll
            for (int b = 0; b < SB; ++b)
                sim[(size_t)(b0 + b) * MEMN + k0 + mloc] = dot[b] * inv;
        }
    }
}

// ---------------------------------------------------------------------------
// Kernel 2: per-batch top-16 (tie -> lowest index), clamp, renormalize.
// One wave per batch; proven selection logic, sim read from workspace.
// ---------------------------------------------------------------------------
__global__ __launch_bounds__(64) void select_kernel(
    const float* __restrict__ sim,
    int* __restrict__ out_ids,
    float* __restrict__ out_w)
{
    const int b = blockIdx.x;
    const int lane_ = threadIdx.x;

    float v0 = sim[(size_t)b * MEMN + lane_];
    float v1 = sim[(size_t)b * MEMN + lane_ + 64];
    float v2 = sim[(size_t)b * MEMN + lane_ + 128];
    float v3 = sim[(size_t)b * MEMN + lane_ + 192];
    int myid = 0;

    for (int r = 0; r < TOPK; ++r) {
        float bv = v0; int bi = lane_;
        if (v1 > bv) { bv = v1; bi = lane_ + 64;  }
        if (v2 > bv) { bv = v2; bi = lane_ + 128; }
        if (v3 > bv) { bv = v3; bi = lane_ + 192; }
        for (int off = 32; off > 0; off >>= 1) {
            const float ov = __shfl_down(bv, off);
            const int   oi = __shfl_down(bi, off);
            if (ov > bv || (ov == bv && oi < bi)) { bv = ov; bi = oi; }
        }
        bi = __shfl(bi, 0);
        if (lane_ == r) myid = bi;
        if ((bi & 63) == lane_) {
            const int slot = bi >> 6;
            if      (slot == 0) v0 = -1e30f;
            else if (slot == 1) v1 = -1e30f;
            else if (slot == 2) v2 = -1e30f;
            else                v3 = -1e30f;
        }
    }

    if (lane_ < TOPK) {
        float val = sim[(size_t)b * MEMN + myid];
        if (val < 0.f) val = 0.f;
        float s = val;
        for (int off = 1; off < TOPK; off <<= 1)
            s += __shfl_xor(s, off);
        out_ids[b * TOPK + lane_] = myid;
        out_w[b * TOPK + lane_]   = val / s;
    }
}

// ---------------------------------------------------------------------------
// Kernel B: ctx[b, col] = sum_k w[b,k] * mem[id[b,k], col]
// Round-1 winning config: 512 blocks x 256 threads, 2 blocks/CU, 4 batch/lane.
// Double-buffered 2x32 KB slabs; stage chunk c+1 overlaps compute of chunk c;
// counted s_waitcnt vmcnt(4) (4 trailing stores) + raw s_barrier.
// XCD swizzle keeps a group's 4 batch-tiles co-resident per XCD.
// ---------------------------------------------------------------------------
__global__ __launch_bounds__(256, 2) void ctx_kernel(
    const float* __restrict__ mem,
    const int* __restrict__ ids,
    const float* __restrict__ wgt,
    float* __restrict__ out)
{
    __shared__ float slab0[MEMN * CCOLS];   // 32 KB
    __shared__ float slab1[MEMN * CCOLS];   // 32 KB

    const int bid  = blockIdx.x;
    const int xcd  = bid & 7;
    const int idx  = bid >> 3;
    const int tile = idx >> 4;                 // 0..3
    const int g    = xcd * 16 + (idx & 15);    // 0..127, tiles of a group co-XCD
    const int b_base = tile * BT;
    const int col0   = g * (NCH * CCOLS);      // 1024-col swath

    const int tid  = threadIdx.x;
    const int wave = tid >> 6, lane = tid & 63;
    const int bg   = lane >> 3;                // batch sub-group 0..7
    const int cg   = lane & 7;                 // col group 0..7 (4 floats each)

    const int bA = b_base + wave * 8 + bg;     // batches bA + {0,32,64,96}

    // (id, w) -> registers for the whole kernel; ids pre-scaled to LDS byte offs
    int   off[4 * TOPK];
    float w[4 * TOPK];
#pragma unroll
    for (int q = 0; q < 4; ++q) {
        const int b = bA + q * 32;
#pragma unroll
        for (int r = 0; r < 4; ++r) {
            int4   iv = *reinterpret_cast<const int4*>(ids + b * TOPK + r * 4);
            float4 wv = *reinterpret_cast<const float4*>(wgt + b * TOPK + r * 4);
            off[q*16 + r*4 + 0] = iv.x * (CCOLS*4) + cg * 16;
            off[q*16 + r*4 + 1] = iv.y * (CCOLS*4) + cg * 16;
            off[q*16 + r*4 + 2] = iv.z * (CCOLS*4) + cg * 16;
            off[q*16 + r*4 + 3] = iv.w * (CCOLS*4) + cg * 16;
            w[q*16 + r*4 + 0] = wv.x; w[q*16 + r*4 + 1] = wv.y;
            w[q*16 + r*4 + 2] = wv.z; w[q*16 + r*4 + 3] = wv.w;
        }
    }

    // stage 256 rows x 128 B into buf; each wave: 8 iters x (8 rows x 128 B)
    auto stage = [&](float* buf, int cb) {
#pragma unroll
        for (int i = 0; i < 8; ++i) {
            const int r = wave * 64 + i * 8 + bg;
            const float* gp = mem + (size_t)r * PROMPT + cb + cg * 4;
            float* lp = buf + (size_t)(wave * 64 + i * 8) * CCOLS + lane * 4;
            __builtin_amdgcn_global_load_lds(
                (const __attribute__((address_space(1))) unsigned int*)gp,
                (__attribute__((address_space(3))) unsigned int*)lp,
                16, 0, 0);
        }
    };

    // gather-accumulate 4 batches x 8 float4-cols from buf, 4 stores
    auto compute = [&](const float* buf, int cb) {
        const char* slb = reinterpret_cast<const char*>(buf);
#pragma unroll
        for (int q = 0; q < 4; ++q) {
            float4 acc;
            acc.x = acc.y = acc.z = acc.w = 0.f;
#pragma unroll
            for (int k = 0; k < TOPK; ++k) {
                const float4 v = *reinterpret_cast<const float4*>(slb + off[q*16 + k]);
                const float ww = w[q*16 + k];
                acc.x += ww * v.x; acc.y += ww * v.y;
                acc.z += ww * v.z; acc.w += ww * v.w;
            }
            const int b = bA + q * 32;
            *reinterpret_cast<float4*>(out + (size_t)b * PROMPT + cb + cg * 4) = acc;
        }
    };

    // prologue: fill slab0 with chunk 0
    stage(slab0, col0);
    asm volatile("s_waitcnt vmcnt(0)" ::: "memory");
    __builtin_amdgcn_s_barrier();
    asm volatile("" ::: "memory");

    for (int c = 0; c < NCH; c += 2) {
        // stage c+1 -> slab1 while computing c from slab0
        stage(slab1, col0 + (c + 1) * CCOLS);
        asm volatile("" ::: "memory");
        compute(slab0, col0 + c * CCOLS);
        asm volatile("s_waitcnt vmcnt(4)" ::: "memory");   // 4 stores may remain
        __builtin_amdgcn_s_barrier();
        asm volatile("" ::: "memory");

        // stage c+2 -> slab0 while computing c+1 from slab1
        if (c + 2 < NCH) stage(slab0, col0 + (c + 2) * CCOLS);
        asm volatile("" ::: "memory");
        compute(slab1, col0 + (c + 1) * CCOLS);
        asm volatile("s_waitcnt vmcnt(4)" ::: "memory");
        __builtin_amdgcn_s_barrier();
        asm volatile("" ::: "memory");
    }
}

extern "C" void kernel_launch(void* const* d_in, const int* in_sizes, int n_in,
                              void* d_out, int out_size, void* d_ws, size_t ws_size,
                              hipStream_t stream) {
    const float* features = (const float*)d_in[0];   // (512, 512)
    const float* keys     = (const float*)d_in[1];   // (256, 512)
    const float* mem      = (const float*)d_in[2];   // (256, 131072)
    float* out = (float*)d_out;                      // (512, 131072)

    char* ws = (char*)d_ws;
    int*   ids = (int*)ws;                               // 32 KB
    float* wgt = (float*)(ws + 32768);                   // 32 KB
    float* sim = (float*)(ws + 65536);                   // 512 KB

    sim_kernel<<<(BATCH / SB) * (MEMN / SK), 256, 0, stream>>>(features, keys, sim);
    select_kernel<<<BATCH, 64, 0, stream>>>(sim, ids, wgt);
    ctx_kernel<<<NTILE * NGRP, 256, 0, stream>>>(mem, ids, wgt, out);
}